// Round 3
// baseline (255.034 us; speedup 1.0000x reference)
//
#include <hip/hip_runtime.h>
#include <hip/hip_bf16.h>
#include <hip/hip_cooperative_groups.h>

namespace cg = cooperative_groups;

#define N_FEAT 128

// Fused: phase 1 projects all nodes (p_src[n] = x[n]·W[0,:128],
// p_trg[n] = x[n]·W[0,128:]); grid.sync(); phase 2 computes per-edge
// sigmoid(p_src[s] + p_trg[t] + b).
//
// 1024 blocks x 256 threads, __launch_bounds__(256,4) -> 4 blocks/CU
// guaranteed co-resident on 256 CUs (cooperative launch validates).
__global__ __launch_bounds__(256, 4) void fused_kernel(
    const float* __restrict__ x, const float* __restrict__ W,
    const int* __restrict__ esrc, const int* __restrict__ etrg,
    const float* __restrict__ b, float* __restrict__ out,
    float* __restrict__ p_src, float* __restrict__ p_trg,
    int n_nodes, int n_edges4)
{
    cg::grid_group grid = cg::this_grid();

    const int nthreads = gridDim.x * blockDim.x;
    // ---- Phase 1: projection. 32 lanes per node, float4 (16 B) loads. ----
    const int nsegs = nthreads >> 5;
    const int seg   = (blockIdx.x * blockDim.x + threadIdx.x) >> 5;
    const int sub   = threadIdx.x & 31;

    // W slices are loop-invariant; hoisted (L1-resident after first touch).
    const float4 ws = *reinterpret_cast<const float4*>(W + 4 * sub);
    const float4 wt = *reinterpret_cast<const float4*>(W + N_FEAT + 4 * sub);

    for (int node = seg; node < n_nodes; node += nsegs) {
        const float4 xv = *reinterpret_cast<const float4*>(
            x + (size_t)node * N_FEAT + 4 * sub);
        float ssrc = fmaf(xv.x, ws.x, fmaf(xv.y, ws.y, fmaf(xv.z, ws.z, xv.w * ws.w)));
        float strg = fmaf(xv.x, wt.x, fmaf(xv.y, wt.y, fmaf(xv.z, wt.z, xv.w * wt.w)));
        #pragma unroll
        for (int off = 16; off > 0; off >>= 1) {
            ssrc += __shfl_down(ssrc, off, 32);
            strg += __shfl_down(strg, off, 32);
        }
        if (sub == 0) {
            p_src[node] = ssrc;
            p_trg[node] = strg;
        }
    }

    __threadfence();   // make table writes device-visible before the barrier
    grid.sync();

    // ---- Phase 2: edges, 4 per thread. ----
    const int tid  = blockIdx.x * blockDim.x + threadIdx.x;
    const float bias = b[0];
    for (int i = tid; i < n_edges4; i += nthreads) {
        const int4 s = reinterpret_cast<const int4*>(esrc)[i];
        const int4 t = reinterpret_cast<const int4*>(etrg)[i];
        float4 o;
        o.x = 1.0f / (1.0f + __expf(-(p_src[s.x] + p_trg[t.x] + bias)));
        o.y = 1.0f / (1.0f + __expf(-(p_src[s.y] + p_trg[t.y] + bias)));
        o.z = 1.0f / (1.0f + __expf(-(p_src[s.z] + p_trg[t.z] + bias)));
        o.w = 1.0f / (1.0f + __expf(-(p_src[s.w] + p_trg[t.w] + bias)));
        reinterpret_cast<float4*>(out)[i] = o;
    }
}

extern "C" void kernel_launch(void* const* d_in, const int* in_sizes, int n_in,
                              void* d_out, int out_size, void* d_ws, size_t ws_size,
                              hipStream_t stream)
{
    // setup_inputs() dict order: input, edge_src_nodes, edge_trg_nodes, W, b
    const float* x    = (const float*)d_in[0];
    const int*   esrc = (const int*)d_in[1];
    const int*   etrg = (const int*)d_in[2];
    const float* W    = (const float*)d_in[3];
    const float* b    = (const float*)d_in[4];
    float* out = (float*)d_out;

    int n_nodes  = in_sizes[0] / N_FEAT;   // 100000
    int n_edges  = in_sizes[1];            // 640000 (divisible by 4)
    int n_edges4 = n_edges / 4;            // 160000

    float* p_src = (float*)d_ws;           // n_nodes floats
    float* p_trg = p_src + n_nodes;        // n_nodes floats

    dim3 grid(1024), block(256);
    void* args[] = { (void*)&x, (void*)&W, (void*)&esrc, (void*)&etrg,
                     (void*)&b, (void*)&out, (void*)&p_src, (void*)&p_trg,
                     (void*)&n_nodes, (void*)&n_edges4 };
    hipLaunchCooperativeKernel((const void*)fused_kernel, grid, block,
                               args, 0, stream);
}

// Round 4
// 100.728 us; speedup vs baseline: 2.5319x; 2.5319x over previous
//
#include <hip/hip_runtime.h>
#include <hip/hip_bf16.h>

#define N_FEAT 128

// Pass 1: per-node projection into an interleaved table:
//   p[n] = { x[n]·W[0,:128], x[n]·W[0,128:] }
// 32 lanes per node, float4 (16 B) loads per lane; 5-step shfl reduction
// within the 32-lane segment; single 8 B store from segment lane 0.
__global__ __launch_bounds__(256) void project_kernel(
    const float* __restrict__ x, const float* __restrict__ W,
    float2* __restrict__ p, int n_nodes)
{
    int gid  = blockIdx.x * blockDim.x + threadIdx.x;
    int node = gid >> 5;           // 32 lanes per node
    int sub  = threadIdx.x & 31;
    if (node >= n_nodes) return;

    const float4 xv = *reinterpret_cast<const float4*>(x + (size_t)node * N_FEAT + 4 * sub);
    const float4 ws = *reinterpret_cast<const float4*>(W + 4 * sub);            // W_src slice
    const float4 wt = *reinterpret_cast<const float4*>(W + N_FEAT + 4 * sub);   // W_trg slice

    float ssrc = fmaf(xv.x, ws.x, fmaf(xv.y, ws.y, fmaf(xv.z, ws.z, xv.w * ws.w)));
    float strg = fmaf(xv.x, wt.x, fmaf(xv.y, wt.y, fmaf(xv.z, wt.z, xv.w * wt.w)));

    #pragma unroll
    for (int off = 16; off > 0; off >>= 1) {
        ssrc += __shfl_down(ssrc, off, 32);
        strg += __shfl_down(strg, off, 32);
    }
    if (sub == 0) {
        p[node] = make_float2(ssrc, strg);
    }
}

// Pass 2: 8 edges per thread. Two int4 loads per index array, scalar
// cache-resident gathers from the 0.8 MB p-table, two float4 stores.
__global__ __launch_bounds__(256) void edge_kernel(
    const int* __restrict__ esrc, const int* __restrict__ etrg,
    const float2* __restrict__ p, const float* __restrict__ b,
    float* __restrict__ out, int n_edges8)
{
    int i = blockIdx.x * blockDim.x + threadIdx.x;
    if (i >= n_edges8) return;
    const int4* esrc4 = reinterpret_cast<const int4*>(esrc);
    const int4* etrg4 = reinterpret_cast<const int4*>(etrg);
    const int4 s0 = esrc4[2 * i],     t0 = etrg4[2 * i];
    const int4 s1 = esrc4[2 * i + 1], t1 = etrg4[2 * i + 1];
    const float bias = b[0];

    float4 o0, o1;
    o0.x = 1.0f / (1.0f + __expf(-(p[s0.x].x + p[t0.x].y + bias)));
    o0.y = 1.0f / (1.0f + __expf(-(p[s0.y].x + p[t0.y].y + bias)));
    o0.z = 1.0f / (1.0f + __expf(-(p[s0.z].x + p[t0.z].y + bias)));
    o0.w = 1.0f / (1.0f + __expf(-(p[s0.w].x + p[t0.w].y + bias)));
    o1.x = 1.0f / (1.0f + __expf(-(p[s1.x].x + p[t1.x].y + bias)));
    o1.y = 1.0f / (1.0f + __expf(-(p[s1.y].x + p[t1.y].y + bias)));
    o1.z = 1.0f / (1.0f + __expf(-(p[s1.z].x + p[t1.z].y + bias)));
    o1.w = 1.0f / (1.0f + __expf(-(p[s1.w].x + p[t1.w].y + bias)));
    float4* out4 = reinterpret_cast<float4*>(out);
    out4[2 * i]     = o0;
    out4[2 * i + 1] = o1;
}

extern "C" void kernel_launch(void* const* d_in, const int* in_sizes, int n_in,
                              void* d_out, int out_size, void* d_ws, size_t ws_size,
                              hipStream_t stream)
{
    // setup_inputs() dict order: input, edge_src_nodes, edge_trg_nodes, W, b
    const float* x    = (const float*)d_in[0];
    const int*   esrc = (const int*)d_in[1];
    const int*   etrg = (const int*)d_in[2];
    const float* W    = (const float*)d_in[3];
    const float* b    = (const float*)d_in[4];
    float* out = (float*)d_out;

    int n_nodes = in_sizes[0] / N_FEAT;   // 100000
    int n_edges = in_sizes[1];            // 640000 (divisible by 8)

    float2* p = (float2*)d_ws;            // n_nodes float2 = 800 KB

    const int threads = 256;
    // 32 lanes per node -> 8 nodes per 256-thread block
    int blocks1 = (n_nodes * 32 + threads - 1) / threads;
    project_kernel<<<blocks1, threads, 0, stream>>>(x, W, p, n_nodes);

    int n_edges8 = n_edges / 8;           // 80000
    int blocks2 = (n_edges8 + threads - 1) / threads;
    edge_kernel<<<blocks2, threads, 0, stream>>>(esrc, etrg, p, b, out, n_edges8);
}